// Round 3
// baseline (327.127 us; speedup 1.0000x reference)
//
#include <hip/hip_runtime.h>
#include <stdint.h>

// Shapes (fixed by the reference)
#define B_  4096
#define V_  5
#define D_  512
#define NN_ (B_ * V_)            // 20480 text rows

// p = exp((dot - 1)/T) = exp2(dot*C - C), C = log2(e)/T
#define C_EXP 20.609929155556620f   // 1.4426950408889634 / 0.07
#define M_SHIFT (1.0f / 0.07f)

typedef _Float16 half8   __attribute__((ext_vector_type(8)));
typedef float    floatx4 __attribute__((ext_vector_type(4)));

// async global->LDS DMA, 16B per lane; LDS dest = wave-uniform base + lane*16
__device__ __forceinline__ void load_lds16(const _Float16* g, _Float16* l) {
  __builtin_amdgcn_global_load_lds(
      (const __attribute__((address_space(1))) unsigned int*)g,
      (__attribute__((address_space(3))) unsigned int*)l,
      16, 0, 0);
}

// ---------------------------------------------------------------------------
// Kernel 1: fused fp32->f16 convert + possum (one pass over the fp32 inputs)
// grid = 10240 x 256: one txt float4 per thread (NN*D/4 = 2,621,440 exact)
// ---------------------------------------------------------------------------
__global__ void cvtpos_kernel(const float* __restrict__ img, const float* __restrict__ txt,
                              _Float16* __restrict__ Ah, _Float16* __restrict__ Bh,
                              float* __restrict__ pos) {
  const int idx = blockIdx.x * 256 + threadIdx.x;
  const int k4  = idx & 127;                 // D/4 = 128
  const int row = idx >> 7;                  // text row = i*V + v
  const int ii  = row / 5;                   // image index (magic-mul)

  float4 t = ((const float4*)txt)[idx];
  float4 g = ((const float4*)img)[ii * 128 + k4];
  float s = t.x * g.x + t.y * g.y + t.z * g.z + t.w * g.w;

  union { _Float16 h[4]; float2 f2; } u;
  u.h[0] = (_Float16)t.x; u.h[1] = (_Float16)t.y;
  u.h[2] = (_Float16)t.z; u.h[3] = (_Float16)t.w;
  ((float2*)Bh)[idx] = u.f2;

  if (idx < (B_ * D_) / 4) {                 // first 524288 threads: img convert
    float4 v = ((const float4*)img)[idx];
    union { _Float16 h[4]; float2 f2; } w;
    w.h[0] = (_Float16)v.x; w.h[1] = (_Float16)v.y;
    w.h[2] = (_Float16)v.z; w.h[3] = (_Float16)v.w;
    ((float2*)Ah)[idx] = w.f2;
  }

  for (int o = 32; o; o >>= 1) s += __shfl_xor(s, o);
  __shared__ float ls[4];
  int lane = threadIdx.x & 63, w = threadIdx.x >> 6;
  if (lane == 0) ls[w] = s;
  __syncthreads();
  if (threadIdx.x == 0)
    atomicAdd(pos, (ls[0] + ls[1] + ls[2] + ls[3]) * M_SHIFT);
}

// ---------------------------------------------------------------------------
// Kernel 2: fused GEMM + exp + row/col partial sums
// 128m x 256n block tile, BK=32, 256 threads = 4 waves (2x2), wave tile 64x128
// XOR-swizzled LDS (chunk ^= (row>>1)&3) so each half-wave phase of a
// ds_read_b128 hits all 8 bank-groups (kills the +4cyc/read conflicts).
// grid = (32 m-tiles, 80 n-tiles); m fastest -> A (4MB f16) stays L2-hot.
// ---------------------------------------------------------------------------
__global__ __launch_bounds__(256, 2)
void gemm_kernel(const _Float16* __restrict__ Ah, const _Float16* __restrict__ Bh,
                 float* __restrict__ row_sum, float* __restrict__ col_sum) {
  __shared__ __align__(16) _Float16 As[128 * 32];   //  8 KB
  __shared__ __align__(16) _Float16 Bs[256 * 32];   // 16 KB
  const int tid  = threadIdx.x;
  const int lane = tid & 63;
  const int w    = tid >> 6;                 // wave 0..3
  const int wm   = w >> 1, wn = w & 1;       // 2x2 wave grid
  const int m0   = blockIdx.x * 128;
  const int n0   = blockIdx.y * 256;

  floatx4 acc[4][8] = {};

  // --- staging addresses (swizzled chunk within each 64B row-segment) ---
  // DMA covers 16 rows x 64B; lane L -> LDS row base+(L>>2), chunk L&3.
  // LDS(r,c) holds global chunk c ^ ((r>>1)&3); base%16==0 so swizzle is lane-only.
  const int sc = (((lane & 3) ^ ((lane >> 3) & 3))) * 8;   // halves
  const _Float16* gA = Ah + (size_t)(m0 + w * 32 + (lane >> 2)) * D_ + sc;
  const _Float16* gB = Bh + (size_t)(n0 + w * 64 + (lane >> 2)) * D_ + sc;
  _Float16* lA = As + (w * 32) * 32;         // wave-uniform LDS bases
  _Float16* lB = Bs + (w * 64) * 32;

  // --- fragment addresses (apply matching un-swizzle) ---
  const int fr = lane & 15;                  // frag m/n index
  const int fj = ((lane >> 4) ^ ((fr >> 1) & 3)) * 8;   // swizzled k-chunk, halves

  for (int kt = 0; kt < 16; ++kt) {
    const int kg = kt * 32;
    load_lds16(gA + kg,            lA);
    load_lds16(gA + kg + 16 * D_,  lA + 16 * 32);
    load_lds16(gB + kg,            lB);
    load_lds16(gB + kg + 16 * D_,  lB + 16 * 32);
    load_lds16(gB + kg + 32 * D_,  lB + 32 * 32);
    load_lds16(gB + kg + 48 * D_,  lB + 48 * 32);
    __syncthreads();   // compiler emits vmcnt(0) drain before s_barrier

    half8 af[4], bf[8];
#pragma unroll
    for (int f = 0; f < 4; ++f)
      af[f] = *(const half8*)(As + (wm * 64 + f * 16 + fr) * 32 + fj);
#pragma unroll
    for (int f = 0; f < 8; ++f)
      bf[f] = *(const half8*)(Bs + (wn * 128 + f * 16 + fr) * 32 + fj);
#pragma unroll
    for (int mf = 0; mf < 4; ++mf)
#pragma unroll
      for (int nf = 0; nf < 8; ++nf)
        acc[mf][nf] = __builtin_amdgcn_mfma_f32_16x16x32_f16(af[mf], bf[nf], acc[mf][nf], 0, 0, 0);
    __syncthreads();   // protect LDS before next stage
  }

  // Epilogue: p = exp2(dot*C - C); C/D layout: col=lane&15, row=(lane>>4)*4+reg
#pragma unroll
  for (int mf = 0; mf < 4; ++mf)
#pragma unroll
    for (int nf = 0; nf < 8; ++nf)
#pragma unroll
      for (int r = 0; r < 4; ++r)
        acc[mf][nf][r] = exp2f(acc[mf][nf][r] * C_EXP - C_EXP);

  // column sums over this wave's 64 rows
  float cs[8];
#pragma unroll
  for (int nf = 0; nf < 8; ++nf) {
    float s = 0.0f;
#pragma unroll
    for (int mf = 0; mf < 4; ++mf)
      s += acc[mf][nf][0] + acc[mf][nf][1] + acc[mf][nf][2] + acc[mf][nf][3];
    s += __shfl_xor(s, 16);
    s += __shfl_xor(s, 32);
    cs[nf] = s;
  }
  {
    int g = lane >> 4;                        // lane group g handles frags g and g+4
    float v1 = (g == 0) ? cs[0] : (g == 1) ? cs[1] : (g == 2) ? cs[2] : cs[3];
    float v2 = (g == 0) ? cs[4] : (g == 1) ? cs[5] : (g == 2) ? cs[6] : cs[7];
    atomicAdd(&col_sum[n0 + wn * 128 + (g << 4) + (lane & 15)], v1);
    atomicAdd(&col_sum[n0 + wn * 128 + ((g + 4) << 4) + (lane & 15)], v2);
  }

  // row sums over this wave's 128 cols
#pragma unroll
  for (int mf = 0; mf < 4; ++mf) {
    floatx4 t = acc[mf][0];
#pragma unroll
    for (int nf = 1; nf < 8; ++nf) t += acc[mf][nf];
#pragma unroll
    for (int r = 0; r < 4; ++r) {
      float s = t[r];
      s += __shfl_xor(s, 1); s += __shfl_xor(s, 2);
      s += __shfl_xor(s, 4); s += __shfl_xor(s, 8);
      t[r] = s;
    }
    if ((lane & 15) < 4) {                    // 16 lanes cover 16 rows of this m-frag
      int q = lane & 3;
      float v = (q == 0) ? t[0] : (q == 1) ? t[1] : (q == 2) ? t[2] : t[3];
      atomicAdd(&row_sum[m0 + wm * 64 + mf * 16 + ((lane >> 4) << 2) + q], v);
    }
  }
}

// ---------------------------------------------------------------------------
// Kernel 3: loss = M + 0.5*(mean log rowsum + mean log colsum - 2*pos/(BV))
// ---------------------------------------------------------------------------
__global__ void finish_kernel(const float* __restrict__ acc, float* __restrict__ out) {
  int tid = threadIdx.x;                     // single block, 1024 threads
  float sA = 0.0f, sB = 0.0f;
  for (int i = tid; i < B_;  i += 1024) sA += logf(acc[i]);
  for (int i = tid; i < NN_; i += 1024) sB += logf(acc[B_ + i]);
  float s = sA * (1.0f / B_) + sB * (1.0f / NN_);
  for (int o = 32; o; o >>= 1) s += __shfl_xor(s, o);
  __shared__ float ls[16];
  int lane = tid & 63, w = tid >> 6;
  if (lane == 0) ls[w] = s;
  __syncthreads();
  if (tid == 0) {
    float tot = 0.0f;
#pragma unroll
    for (int i = 0; i < 16; ++i) tot += ls[i];
    float pos = acc[B_ + NN_];
    out[0] = M_SHIFT + 0.5f * (tot - 2.0f * pos / (float)NN_);
  }
}

// ---------------------------------------------------------------------------
extern "C" void kernel_launch(void* const* d_in, const int* in_sizes, int n_in,
                              void* d_out, int out_size, void* d_ws, size_t ws_size,
                              hipStream_t stream) {
  const float* img = (const float*)d_in[0];   // (4096, 512) fp32
  const float* txt = (const float*)d_in[1];   // (4096, 5, 512) fp32

  // workspace: [ img_f16 | txt_f16 | row_sum(4096) col_sum(20480) pos(1) ]
  const size_t halfBytes = (size_t)(B_ * D_ + NN_ * D_) * 2;      // 25,165,824
  const size_t needBytes = halfBytes + (size_t)(B_ + NN_ + 1) * 4;
  if (ws_size < needBytes) return;            // fail loudly (absmax), don't fault

  _Float16* Ah  = (_Float16*)d_ws;            // B*D halves
  _Float16* Bh  = Ah + B_ * D_;               // NN*D halves
  float* acc    = (float*)((char*)d_ws + halfBytes);
  float* row_s  = acc;
  float* col_s  = acc + B_;
  float* pos    = acc + B_ + NN_;

  hipMemsetAsync(acc, 0, (size_t)(B_ + NN_ + 1) * 4, stream);
  cvtpos_kernel<<<10240, 256, 0, stream>>>(img, txt, Ah, Bh, pos);
  gemm_kernel  <<<dim3(32, 80), 256, 0, stream>>>(Ah, Bh, row_s, col_s);
  finish_kernel<<<1, 1024, 0, stream>>>(acc, (float*)d_out);
}

// Round 5
// 272.107 us; speedup vs baseline: 1.2022x; 1.2022x over previous
//
#include <hip/hip_runtime.h>
#include <stdint.h>

// Shapes (fixed by the reference)
#define B_  4096
#define V_  5
#define D_  512
#define NN_ (B_ * V_)            // 20480 text rows
#define NPART_ 10240             // cvtpos partial-sum blocks

// p = exp((dot - 1)/T) = exp2(dot*C - C), C = log2(e)/T
#define C_EXP 20.609929155556620f   // 1.4426950408889634 / 0.07
#define M_SHIFT (1.0f / 0.07f)

typedef _Float16 half8   __attribute__((ext_vector_type(8)));
typedef float    floatx4 __attribute__((ext_vector_type(4)));

// async global->LDS DMA, 16B per lane; LDS dest = wave-uniform base + lane*16
__device__ __forceinline__ void load_lds16(const _Float16* g, _Float16* l) {
  __builtin_amdgcn_global_load_lds(
      (const __attribute__((address_space(1))) unsigned int*)g,
      (__attribute__((address_space(3))) unsigned int*)l,
      16, 0, 0);
}

// ---------------------------------------------------------------------------
// Kernel 1: fused fp32->f16 convert + possum partials.
// grid = 10240 x 256: one txt float4 per thread (NN*D/4 = 2,621,440 exact).
// NO global atomics — each block writes part[blockIdx.x] (round-3 showed the
// 10240 same-address atomicAdds serialized at ~13ns each = the whole 137us).
// ---------------------------------------------------------------------------
__global__ void cvtpos_kernel(const float* __restrict__ img, const float* __restrict__ txt,
                              _Float16* __restrict__ Ah, _Float16* __restrict__ Bh,
                              float* __restrict__ part) {
  const int idx = blockIdx.x * 256 + threadIdx.x;
  const int k4  = idx & 127;                 // D/4 = 128
  const int row = idx >> 7;                  // text row = i*V + v
  const int ii  = row / 5;                   // image index (magic-mul)

  float4 t = ((const float4*)txt)[idx];
  float4 g = ((const float4*)img)[ii * 128 + k4];
  float s = t.x * g.x + t.y * g.y + t.z * g.z + t.w * g.w;

  union { _Float16 h[4]; float2 f2; } u;
  u.h[0] = (_Float16)t.x; u.h[1] = (_Float16)t.y;
  u.h[2] = (_Float16)t.z; u.h[3] = (_Float16)t.w;
  ((float2*)Bh)[idx] = u.f2;

  if (idx < (B_ * D_) / 4) {                 // first 524288 threads: img convert
    float4 v = ((const float4*)img)[idx];
    union { _Float16 h[4]; float2 f2; } w;
    w.h[0] = (_Float16)v.x; w.h[1] = (_Float16)v.y;
    w.h[2] = (_Float16)v.z; w.h[3] = (_Float16)v.w;
    ((float2*)Ah)[idx] = w.f2;
  }

  for (int o = 32; o; o >>= 1) s += __shfl_xor(s, o);
  __shared__ float ls[4];
  int lane = threadIdx.x & 63, w = threadIdx.x >> 6;
  if (lane == 0) ls[w] = s;
  __syncthreads();
  if (threadIdx.x == 0)
    part[blockIdx.x] = ls[0] + ls[1] + ls[2] + ls[3];   // raw dot-sum, no atomic
}

// ---------------------------------------------------------------------------
// Kernel 2: fused GEMM + exp + row/col partial sums
// 128x128 tile, BK=32, 256 threads = 4 waves (2x2), wave tile 64x64.
// B staged in LDS via global_load_lds with XOR bank swizzle (verified 0
// conflicts in round 3). A fragments loaded DIRECT global->VGPR (A-tile is
// L1/L2-resident: 8 KB/kt/block) — halves LDS traffic, halves DMA count, and
// the A loads overlap the DMA drain before the barrier.
// grid = (32 m-tiles, 160 n-tiles); m fastest -> B-tile shared by 32 blocks.
// ---------------------------------------------------------------------------
__global__ __launch_bounds__(256, 3)
void gemm_kernel(const _Float16* __restrict__ Ah, const _Float16* __restrict__ Bh,
                 float* __restrict__ row_sum, float* __restrict__ col_sum) {
  __shared__ __align__(16) _Float16 Bs[128 * 32];   // 8 KB
  const int tid  = threadIdx.x;
  const int lane = tid & 63;
  const int w    = tid >> 6;                 // wave 0..3
  const int wm   = w >> 1, wn = w & 1;       // 2x2 wave grid
  const int m0   = blockIdx.x * 128;
  const int n0   = blockIdx.y * 128;

  floatx4 acc[4][4] = {};

  // --- B staging (swizzled): lane L -> LDS row L>>2, chunk L&3; the global
  // chunk fetched is (L&3)^((L>>3)&3), i.e. LDS(r,c) = global chunk c^((r>>1)&3).
  const int sc = ((lane & 3) ^ ((lane >> 3) & 3)) * 8;     // halves
  const _Float16* gB = Bh + (size_t)(n0 + w * 32 + (lane >> 2)) * D_ + sc;
  _Float16* lB = Bs + (w * 32) * 32;         // wave-uniform LDS base

  // --- fragment addressing ---
  const int fr = lane & 15;                  // frag m/n index (lane&15)
  const int fk = (lane >> 4) * 8;            // frag k-offset, halves (global A)
  const int fj = ((lane >> 4) ^ ((fr >> 1) & 3)) * 8;      // un-swizzled Bs chunk
  const _Float16* gA = Ah + (size_t)(m0 + wm * 64 + fr) * D_ + fk;

  for (int kt = 0; kt < 16; ++kt) {
    const int kg = kt * 32;
    load_lds16(gB + kg,           lB);
    load_lds16(gB + kg + 16 * D_, lB + 16 * 32);

    half8 af[4];
#pragma unroll
    for (int f = 0; f < 4; ++f)
      af[f] = *(const half8*)(gA + kg + f * 16 * D_);      // direct global->VGPR

    __syncthreads();   // drains DMA (and af) before Bs reads

    half8 bf[4];
#pragma unroll
    for (int f = 0; f < 4; ++f)
      bf[f] = *(const half8*)(Bs + (wn * 64 + f * 16 + fr) * 32 + fj);
#pragma unroll
    for (int mf = 0; mf < 4; ++mf)
#pragma unroll
      for (int nf = 0; nf < 4; ++nf)
        acc[mf][nf] = __builtin_amdgcn_mfma_f32_16x16x32_f16(af[mf], bf[nf], acc[mf][nf], 0, 0, 0);
    __syncthreads();   // protect Bs before next stage
  }

  // Epilogue: p = exp2(dot*C - C); C/D layout: col=lane&15, row=(lane>>4)*4+reg
#pragma unroll
  for (int mf = 0; mf < 4; ++mf)
#pragma unroll
    for (int nf = 0; nf < 4; ++nf)
#pragma unroll
      for (int r = 0; r < 4; ++r)
        acc[mf][nf][r] = exp2f(acc[mf][nf][r] * C_EXP - C_EXP);

  // column sums over this wave's 64 rows
  float cs[4];
#pragma unroll
  for (int nf = 0; nf < 4; ++nf) {
    float s = 0.0f;
#pragma unroll
    for (int mf = 0; mf < 4; ++mf)
      s += acc[mf][nf][0] + acc[mf][nf][1] + acc[mf][nf][2] + acc[mf][nf][3];
    s += __shfl_xor(s, 16);
    s += __shfl_xor(s, 32);
    cs[nf] = s;
  }
  {
    int g = lane >> 4;                        // lane group g holds frag g's sums
    float v = (g == 0) ? cs[0] : (g == 1) ? cs[1] : (g == 2) ? cs[2] : cs[3];
    atomicAdd(&col_sum[n0 + wn * 64 + (g << 4) + (lane & 15)], v);
  }

  // row sums over this wave's 64 cols
#pragma unroll
  for (int mf = 0; mf < 4; ++mf) {
    floatx4 t = acc[mf][0] + acc[mf][1] + acc[mf][2] + acc[mf][3];
#pragma unroll
    for (int r = 0; r < 4; ++r) {
      float s = t[r];
      s += __shfl_xor(s, 1); s += __shfl_xor(s, 2);
      s += __shfl_xor(s, 4); s += __shfl_xor(s, 8);
      t[r] = s;
    }
    if ((lane & 15) < 4) {                    // 16 lanes cover 16 rows of this m-frag
      int q = lane & 3;
      float v = (q == 0) ? t[0] : (q == 1) ? t[1] : (q == 2) ? t[2] : t[3];
      atomicAdd(&row_sum[m0 + wm * 64 + mf * 16 + ((lane >> 4) << 2) + q], v);
    }
  }
}

// ---------------------------------------------------------------------------
// Kernel 3: loss = M + 0.5*(mean log rowsum + mean log colsum - 2*pos/(BV))
// pos = M_SHIFT * sum(part).  All linear -> single fused block reduction.
// ---------------------------------------------------------------------------
__global__ void finish_kernel(const float* __restrict__ acc, const float* __restrict__ part,
                              float* __restrict__ out) {
  int tid = threadIdx.x;                     // single block, 1024 threads
  float sA = 0.0f, sB = 0.0f, sP = 0.0f;
  for (int i = tid; i < B_;     i += 1024) sA += logf(acc[i]);
  for (int i = tid; i < NN_;    i += 1024) sB += logf(acc[B_ + i]);
  for (int i = tid; i < NPART_; i += 1024) sP += part[i];
  float s = sA * (1.0f / B_) + sB * (1.0f / NN_)
          - sP * (2.0f * M_SHIFT / (float)NN_);
  for (int o = 32; o; o >>= 1) s += __shfl_xor(s, o);
  __shared__ float ls[16];
  int lane = tid & 63, w = tid >> 6;
  if (lane == 0) ls[w] = s;
  __syncthreads();
  if (tid == 0) {
    float tot = 0.0f;
#pragma unroll
    for (int i = 0; i < 16; ++i) tot += ls[i];
    out[0] = M_SHIFT + 0.5f * tot;
  }
}

// ---------------------------------------------------------------------------
extern "C" void kernel_launch(void* const* d_in, const int* in_sizes, int n_in,
                              void* d_out, int out_size, void* d_ws, size_t ws_size,
                              hipStream_t stream) {
  const float* img = (const float*)d_in[0];   // (4096, 512) fp32
  const float* txt = (const float*)d_in[1];   // (4096, 5, 512) fp32

  // workspace: [ img_f16 | txt_f16 | row_sum(4096) col_sum(20480) part(10240) ]
  const size_t halfBytes = (size_t)(B_ * D_ + NN_ * D_) * 2;      // 25,165,824
  const size_t needBytes = halfBytes + (size_t)(B_ + NN_ + NPART_) * 4;
  if (ws_size < needBytes) return;            // fail loudly (absmax), don't fault

  _Float16* Ah  = (_Float16*)d_ws;            // B*D halves
  _Float16* Bh  = Ah + B_ * D_;               // NN*D halves
  float* acc    = (float*)((char*)d_ws + halfBytes);
  float* row_s  = acc;                        // [0, B_)
  float* col_s  = acc + B_;                   // [B_, B_+NN_)
  float* part   = acc + B_ + NN_;             // [B_+NN_, +NPART_)

  hipMemsetAsync(acc, 0, (size_t)(B_ + NN_) * 4, stream);   // row/col sums only
  cvtpos_kernel<<<NPART_, 256, 0, stream>>>(img, txt, Ah, Bh, part);
  gemm_kernel  <<<dim3(32, 160), 256, 0, stream>>>(Ah, Bh, row_s, col_s);
  finish_kernel<<<1, 1024, 0, stream>>>(acc, part, (float*)d_out);
}

// Round 6
// 217.630 us; speedup vs baseline: 1.5031x; 1.2503x over previous
//
#include <hip/hip_runtime.h>
#include <stdint.h>

// Shapes (fixed by the reference)
#define B_  4096
#define V_  5
#define D_  512
#define NN_ (B_ * V_)            // 20480 text rows
#define NPART_ 10240             // cvtpos partial-sum blocks

// p = exp((dot - 1)/T) = exp2(dot*C - C), C = log2(e)/T
#define C_EXP 20.609929155556620f   // 1.4426950408889634 / 0.07
#define M_SHIFT (1.0f / 0.07f)

typedef _Float16 half8   __attribute__((ext_vector_type(8)));
typedef float    floatx4 __attribute__((ext_vector_type(4)));

// async global->LDS DMA, 16B per lane; LDS dest = wave-uniform base + lane*16
__device__ __forceinline__ void load_lds16(const _Float16* g, _Float16* l) {
  __builtin_amdgcn_global_load_lds(
      (const __attribute__((address_space(1))) unsigned int*)g,
      (__attribute__((address_space(3))) unsigned int*)l,
      16, 0, 0);
}

// ---------------------------------------------------------------------------
// Kernel 1: fused fp32->f16 convert + possum partials + accumulator zeroing.
// grid = 10240 x 256: one txt float4 per thread (NN*D/4 = 2,621,440 exact).
// Per-block partial store (round 3 proved same-address atomics serialize).
// ---------------------------------------------------------------------------
__global__ void cvtpos_kernel(const float* __restrict__ img, const float* __restrict__ txt,
                              _Float16* __restrict__ Ah, _Float16* __restrict__ Bh,
                              float* __restrict__ acc, float* __restrict__ part) {
  const int idx = blockIdx.x * 256 + threadIdx.x;
  if (idx < B_ + NN_) acc[idx] = 0.0f;       // zero row/col sums (replaces memset)
  const int k4  = idx & 127;                 // D/4 = 128
  const int row = idx >> 7;                  // text row = i*V + v
  const int ii  = row / 5;                   // image index (magic-mul)

  float4 t = ((const float4*)txt)[idx];
  float4 g = ((const float4*)img)[ii * 128 + k4];
  float s = t.x * g.x + t.y * g.y + t.z * g.z + t.w * g.w;

  union { _Float16 h[4]; float2 f2; } u;
  u.h[0] = (_Float16)t.x; u.h[1] = (_Float16)t.y;
  u.h[2] = (_Float16)t.z; u.h[3] = (_Float16)t.w;
  ((float2*)Bh)[idx] = u.f2;

  if (idx < (B_ * D_) / 4) {                 // first 524288 threads: img convert
    float4 v = ((const float4*)img)[idx];
    union { _Float16 h[4]; float2 f2; } w;
    w.h[0] = (_Float16)v.x; w.h[1] = (_Float16)v.y;
    w.h[2] = (_Float16)v.z; w.h[3] = (_Float16)v.w;
    ((float2*)Ah)[idx] = w.f2;
  }

  for (int o = 32; o; o >>= 1) s += __shfl_xor(s, o);
  __shared__ float ls[4];
  int lane = threadIdx.x & 63, w = threadIdx.x >> 6;
  if (lane == 0) ls[w] = s;
  __syncthreads();
  if (threadIdx.x == 0)
    part[blockIdx.x] = ls[0] + ls[1] + ls[2] + ls[3];   // raw dot-sum, no atomic
}

// ---------------------------------------------------------------------------
// Kernel 2: fused GEMM + exp + row/col partial sums
// Round-2 structure (128x128 tile, BK=32, A AND B DMA-staged in LDS, 4 waves
// 2x2, wave tile 64x64) + round-3's XOR bank swizzle (verified 0 conflicts,
// verified correct). Round 5 proved direct global A-frags regress (barrier
// vmcnt drain serializes L2 latency) — both operands stay in LDS.
// grid = (32 m-tiles, 160 n-tiles); m fastest -> B-tile shared by 32 blocks.
// ---------------------------------------------------------------------------
__global__ __launch_bounds__(256, 4)
void gemm_kernel(const _Float16* __restrict__ Ah, const _Float16* __restrict__ Bh,
                 float* __restrict__ row_sum, float* __restrict__ col_sum) {
  __shared__ __align__(16) _Float16 As[128 * 32];   // 8 KB
  __shared__ __align__(16) _Float16 Bs[128 * 32];   // 8 KB
  const int tid  = threadIdx.x;
  const int lane = tid & 63;
  const int w    = tid >> 6;                 // wave 0..3
  const int wm   = w >> 1, wn = w & 1;       // 2x2 wave grid
  const int m0   = blockIdx.x * 128;
  const int n0   = blockIdx.y * 128;

  floatx4 acc[4][4] = {};

  // --- staging (swizzled): lane L -> LDS row L>>2, chunk L&3; global chunk
  // fetched is (L&3)^((L>>3)&3), i.e. LDS(r,c) = global chunk c^((r>>1)&3).
  const int sc = ((lane & 3) ^ ((lane >> 3) & 3)) * 8;     // halves
  const _Float16* gA = Ah + (size_t)(m0 + w * 32 + (lane >> 2)) * D_ + sc;
  const _Float16* gB = Bh + (size_t)(n0 + w * 32 + (lane >> 2)) * D_ + sc;
  _Float16* lA = As + (w * 32) * 32;         // wave-uniform LDS bases
  _Float16* lB = Bs + (w * 32) * 32;

  // --- fragment addressing (matching un-swizzle) ---
  const int fr = lane & 15;                  // frag m/n index (lane&15)
  const int fj = ((lane >> 4) ^ ((fr >> 1) & 3)) * 8;      // swizzled k-chunk

  for (int kt = 0; kt < 16; ++kt) {
    const int kg = kt * 32;
    load_lds16(gA + kg,           lA);
    load_lds16(gA + kg + 16 * D_, lA + 16 * 32);
    load_lds16(gB + kg,           lB);
    load_lds16(gB + kg + 16 * D_, lB + 16 * 32);
    __syncthreads();   // compiler emits vmcnt(0) drain before s_barrier

    half8 af[4], bf[4];
#pragma unroll
    for (int f = 0; f < 4; ++f) {
      af[f] = *(const half8*)(As + (wm * 64 + f * 16 + fr) * 32 + fj);
      bf[f] = *(const half8*)(Bs + (wn * 64 + f * 16 + fr) * 32 + fj);
    }
#pragma unroll
    for (int mf = 0; mf < 4; ++mf)
#pragma unroll
      for (int nf = 0; nf < 4; ++nf)
        acc[mf][nf] = __builtin_amdgcn_mfma_f32_16x16x32_f16(af[mf], bf[nf], acc[mf][nf], 0, 0, 0);
    __syncthreads();   // protect LDS before next stage
  }

  // Epilogue: p = exp2(dot*C - C); C/D layout: col=lane&15, row=(lane>>4)*4+reg
#pragma unroll
  for (int mf = 0; mf < 4; ++mf)
#pragma unroll
    for (int nf = 0; nf < 4; ++nf)
#pragma unroll
      for (int r = 0; r < 4; ++r)
        acc[mf][nf][r] = exp2f(acc[mf][nf][r] * C_EXP - C_EXP);

  // column sums over this wave's 64 rows
  float cs[4];
#pragma unroll
  for (int nf = 0; nf < 4; ++nf) {
    float s = 0.0f;
#pragma unroll
    for (int mf = 0; mf < 4; ++mf)
      s += acc[mf][nf][0] + acc[mf][nf][1] + acc[mf][nf][2] + acc[mf][nf][3];
    s += __shfl_xor(s, 16);
    s += __shfl_xor(s, 32);
    cs[nf] = s;
  }
  {
    int g = lane >> 4;                        // lane group g holds frag g's sums
    float v = (g == 0) ? cs[0] : (g == 1) ? cs[1] : (g == 2) ? cs[2] : cs[3];
    atomicAdd(&col_sum[n0 + wn * 64 + (g << 4) + (lane & 15)], v);
  }

  // row sums over this wave's 64 cols
#pragma unroll
  for (int mf = 0; mf < 4; ++mf) {
    floatx4 t = acc[mf][0] + acc[mf][1] + acc[mf][2] + acc[mf][3];
#pragma unroll
    for (int r = 0; r < 4; ++r) {
      float s = t[r];
      s += __shfl_xor(s, 1); s += __shfl_xor(s, 2);
      s += __shfl_xor(s, 4); s += __shfl_xor(s, 8);
      t[r] = s;
    }
    if ((lane & 15) < 4) {                    // 16 lanes cover 16 rows of this m-frag
      int q = lane & 3;
      float v = (q == 0) ? t[0] : (q == 1) ? t[1] : (q == 2) ? t[2] : t[3];
      atomicAdd(&row_sum[m0 + wm * 64 + mf * 16 + ((lane >> 4) << 2) + q], v);
    }
  }
}

// ---------------------------------------------------------------------------
// Kernel 3: loss = M + 0.5*(mean log rowsum + mean log colsum - 2*pos/(BV))
// pos = M_SHIFT * sum(part).  All linear -> single fused block reduction.
// ---------------------------------------------------------------------------
__global__ void finish_kernel(const float* __restrict__ acc, const float* __restrict__ part,
                              float* __restrict__ out) {
  int tid = threadIdx.x;                     // single block, 1024 threads
  float sA = 0.0f, sB = 0.0f, sP = 0.0f;
  for (int i = tid; i < B_;     i += 1024) sA += logf(acc[i]);
  for (int i = tid; i < NN_;    i += 1024) sB += logf(acc[B_ + i]);
  for (int i = tid; i < NPART_; i += 1024) sP += part[i];
  float s = sA * (1.0f / B_) + sB * (1.0f / NN_)
          - sP * (2.0f * M_SHIFT / (float)NN_);
  for (int o = 32; o; o >>= 1) s += __shfl_xor(s, o);
  __shared__ float ls[16];
  int lane = tid & 63, w = tid >> 6;
  if (lane == 0) ls[w] = s;
  __syncthreads();
  if (tid == 0) {
    float tot = 0.0f;
#pragma unroll
    for (int i = 0; i < 16; ++i) tot += ls[i];
    out[0] = M_SHIFT + 0.5f * tot;
  }
}

// ---------------------------------------------------------------------------
extern "C" void kernel_launch(void* const* d_in, const int* in_sizes, int n_in,
                              void* d_out, int out_size, void* d_ws, size_t ws_size,
                              hipStream_t stream) {
  const float* img = (const float*)d_in[0];   // (4096, 512) fp32
  const float* txt = (const float*)d_in[1];   // (4096, 5, 512) fp32

  // workspace: [ img_f16 | txt_f16 | row_sum(4096) col_sum(20480) part(10240) ]
  const size_t halfBytes = (size_t)(B_ * D_ + NN_ * D_) * 2;      // 25,165,824
  const size_t needBytes = halfBytes + (size_t)(B_ + NN_ + NPART_) * 4;
  if (ws_size < needBytes) return;            // fail loudly (absmax), don't fault

  _Float16* Ah  = (_Float16*)d_ws;            // B*D halves
  _Float16* Bh  = Ah + B_ * D_;               // NN*D halves
  float* acc    = (float*)((char*)d_ws + halfBytes);
  float* row_s  = acc;                        // [0, B_)
  float* col_s  = acc + B_;                   // [B_, B_+NN_)
  float* part   = acc + B_ + NN_;             // [B_+NN_, +NPART_)

  cvtpos_kernel<<<NPART_, 256, 0, stream>>>(img, txt, Ah, Bh, acc, part);
  gemm_kernel  <<<dim3(32, 160), 256, 0, stream>>>(Ah, Bh, row_s, col_s);
  finish_kernel<<<1, 1024, 0, stream>>>(acc, part, (float*)d_out);
}

// Round 7
// 210.066 us; speedup vs baseline: 1.5573x; 1.0360x over previous
//
#include <hip/hip_runtime.h>
#include <stdint.h>

// Shapes (fixed by the reference)
#define B_  4096
#define V_  5
#define D_  512
#define NN_ (B_ * V_)            // 20480 text rows
#define NPART_ 2560              // cvtpos blocks (grid-stride x4)

// p = exp((dot - 1)/T) = exp2(dot*C - C), C = log2(e)/T
#define C_EXP 20.609929155556620f   // 1.4426950408889634 / 0.07
#define M_SHIFT (1.0f / 0.07f)

typedef _Float16 half8   __attribute__((ext_vector_type(8)));
typedef float    floatx4 __attribute__((ext_vector_type(4)));

// async global->LDS DMA, 16B per lane; LDS dest = wave-uniform base + lane*16
__device__ __forceinline__ void load_lds16(const _Float16* g, _Float16* l) {
  __builtin_amdgcn_global_load_lds(
      (const __attribute__((address_space(1))) unsigned int*)g,
      (__attribute__((address_space(3))) unsigned int*)l,
      16, 0, 0);
}

// ---------------------------------------------------------------------------
// Kernel 1: fused fp32->f16 convert + possum partials + accumulator zeroing.
// 2560 blocks x 256 threads, each thread 4 float4s (grid-stride, exact cover
// of NN*D/4 = 2,621,440). Fewer blocks = less per-workgroup dispatch overhead
// (r6 left ~86us in non-GEMM kernels with 10240 single-shot blocks).
// ---------------------------------------------------------------------------
__global__ void cvtpos_kernel(const float* __restrict__ img, const float* __restrict__ txt,
                              _Float16* __restrict__ Ah, _Float16* __restrict__ Bh,
                              float* __restrict__ acc, float* __restrict__ part) {
  const int tid0 = blockIdx.x * 256 + threadIdx.x;
  if (tid0 < B_ + NN_) acc[tid0] = 0.0f;     // zero row/col sums (replaces memset)

  float s = 0.0f;
  const int n4 = (NN_ * D_) / 4;
#pragma unroll
  for (int it = 0; it < 4; ++it) {           // 4 * 655360 = n4 exactly
    const int i  = tid0 + it * (NPART_ * 256);
    const int k4  = i & 127;                 // D/4 = 128
    const int row = i >> 7;                  // text row = i*V + v
    const int ii  = row / 5;                 // image index (magic-mul)
    float4 t = ((const float4*)txt)[i];
    float4 g = ((const float4*)img)[ii * 128 + k4];
    s += t.x * g.x + t.y * g.y + t.z * g.z + t.w * g.w;

    union { _Float16 h[4]; float2 f2; } u;
    u.h[0] = (_Float16)t.x; u.h[1] = (_Float16)t.y;
    u.h[2] = (_Float16)t.z; u.h[3] = (_Float16)t.w;
    ((float2*)Bh)[i] = u.f2;

    if (i < (B_ * D_) / 4) {                 // img convert (hits only it==0)
      float4 v = ((const float4*)img)[i];
      union { _Float16 h[4]; float2 f2; } wq;
      wq.h[0] = (_Float16)v.x; wq.h[1] = (_Float16)v.y;
      wq.h[2] = (_Float16)v.z; wq.h[3] = (_Float16)v.w;
      ((float2*)Ah)[i] = wq.f2;
    }
  }

  for (int o = 32; o; o >>= 1) s += __shfl_xor(s, o);
  __shared__ float ls[4];
  int lane = threadIdx.x & 63, w = threadIdx.x >> 6;
  if (lane == 0) ls[w] = s;
  __syncthreads();
  if (threadIdx.x == 0)
    part[blockIdx.x] = ls[0] + ls[1] + ls[2] + ls[3];   // raw dot-sum, no atomic
}

// ---------------------------------------------------------------------------
// Kernel 2: fused GEMM + exp + row/col partial sums — DOUBLE-BUFFERED LDS.
// 128x128 tile, BK=32, 4 waves (2x2), wave tile 64x64, XOR bank swizzle
// (0 conflicts, verified r3/r6). ONE barrier per kt: the vmcnt(0) drain at
// the top-of-kt barrier waits on DMAs issued a full compute phase earlier
// (r6 showed 2-barrier structure = 60% of cycles in barrier drains).
// grid = (32 m-tiles, 160 n-tiles); m fastest -> B-tile shared by 32 blocks.
// ---------------------------------------------------------------------------
__global__ __launch_bounds__(256, 4)
void gemm_kernel(const _Float16* __restrict__ Ah, const _Float16* __restrict__ Bh,
                 float* __restrict__ row_sum, float* __restrict__ col_sum) {
  __shared__ __align__(16) _Float16 As[2][128 * 32];   // 16 KB
  __shared__ __align__(16) _Float16 Bs[2][128 * 32];   // 16 KB
  const int tid  = threadIdx.x;
  const int lane = tid & 63;
  const int w    = tid >> 6;                 // wave 0..3
  const int wm   = w >> 1, wn = w & 1;       // 2x2 wave grid
  const int m0   = blockIdx.x * 128;
  const int n0   = blockIdx.y * 128;

  floatx4 acc[4][4] = {};

  // --- staging (swizzled): lane L -> LDS row L>>2, chunk L&3; global chunk
  // fetched is (L&3)^((L>>3)&3), i.e. LDS(r,c) = global chunk c^((r>>1)&3).
  const int sc = ((lane & 3) ^ ((lane >> 3) & 3)) * 8;     // halves
  const _Float16* gA = Ah + (size_t)(m0 + w * 32 + (lane >> 2)) * D_ + sc;
  const _Float16* gB = Bh + (size_t)(n0 + w * 32 + (lane >> 2)) * D_ + sc;
  const int lofs = (w * 32) * 32;            // wave-uniform LDS offset

  // --- fragment addressing (matching un-swizzle) ---
  const int fr = lane & 15;                  // frag m/n index (lane&15)
  const int fj = ((lane >> 4) ^ ((fr >> 1) & 3)) * 8;      // swizzled k-chunk

  // prefetch kt=0 into buffer 0
  load_lds16(gA,           &As[0][lofs]);
  load_lds16(gA + 16 * D_, &As[0][lofs + 16 * 32]);
  load_lds16(gB,           &Bs[0][lofs]);
  load_lds16(gB + 16 * D_, &Bs[0][lofs + 16 * 32]);

  for (int kt = 0; kt < 16; ++kt) {
    const int p = kt & 1;
    __syncthreads();   // drains the DMA for buf p (issued one full kt ago)

    if (kt < 15) {     // stage kt+1 into the other buffer (no reader until
      const int kg = (kt + 1) * 32;          // after the NEXT barrier)
      load_lds16(gA + kg,           &As[1 - p][lofs]);
      load_lds16(gA + kg + 16 * D_, &As[1 - p][lofs + 16 * 32]);
      load_lds16(gB + kg,           &Bs[1 - p][lofs]);
      load_lds16(gB + kg + 16 * D_, &Bs[1 - p][lofs + 16 * 32]);
    }

    half8 af[4], bf[4];
#pragma unroll
    for (int f = 0; f < 4; ++f) {
      af[f] = *(const half8*)(&As[p][(wm * 64 + f * 16 + fr) * 32 + fj]);
      bf[f] = *(const half8*)(&Bs[p][(wn * 64 + f * 16 + fr) * 32 + fj]);
    }
#pragma unroll
    for (int mf = 0; mf < 4; ++mf)
#pragma unroll
      for (int nf = 0; nf < 4; ++nf)
        acc[mf][nf] = __builtin_amdgcn_mfma_f32_16x16x32_f16(af[mf], bf[nf], acc[mf][nf], 0, 0, 0);
  }

  // Epilogue: p = exp2(dot*C - C); C/D layout: col=lane&15, row=(lane>>4)*4+reg
#pragma unroll
  for (int mf = 0; mf < 4; ++mf)
#pragma unroll
    for (int nf = 0; nf < 4; ++nf)
#pragma unroll
      for (int r = 0; r < 4; ++r)
        acc[mf][nf][r] = exp2f(acc[mf][nf][r] * C_EXP - C_EXP);

  // column sums over this wave's 64 rows
  float cs[4];
#pragma unroll
  for (int nf = 0; nf < 4; ++nf) {
    float s = 0.0f;
#pragma unroll
    for (int mf = 0; mf < 4; ++mf)
      s += acc[mf][nf][0] + acc[mf][nf][1] + acc[mf][nf][2] + acc[mf][nf][3];
    s += __shfl_xor(s, 16);
    s += __shfl_xor(s, 32);
    cs[nf] = s;
  }
  {
    int g = lane >> 4;                        // lane group g holds frag g's sums
    float v = (g == 0) ? cs[0] : (g == 1) ? cs[1] : (g == 2) ? cs[2] : cs[3];
    atomicAdd(&col_sum[n0 + wn * 64 + (g << 4) + (lane & 15)], v);
  }

  // row sums over this wave's 64 cols
#pragma unroll
  for (int mf = 0; mf < 4; ++mf) {
    floatx4 t = acc[mf][0] + acc[mf][1] + acc[mf][2] + acc[mf][3];
#pragma unroll
    for (int r = 0; r < 4; ++r) {
      float s = t[r];
      s += __shfl_xor(s, 1); s += __shfl_xor(s, 2);
      s += __shfl_xor(s, 4); s += __shfl_xor(s, 8);
      t[r] = s;
    }
    if ((lane & 15) < 4) {                    // 16 lanes cover 16 rows of this m-frag
      int q = lane & 3;
      float v = (q == 0) ? t[0] : (q == 1) ? t[1] : (q == 2) ? t[2] : t[3];
      atomicAdd(&row_sum[m0 + wm * 64 + mf * 16 + ((lane >> 4) << 2) + q], v);
    }
  }
}

// ---------------------------------------------------------------------------
// Kernel 3: loss = M + 0.5*(mean log rowsum + mean log colsum - 2*pos/(BV))
// pos = M_SHIFT * sum(part).  All linear -> single fused block reduction.
// ---------------------------------------------------------------------------
__global__ void finish_kernel(const float* __restrict__ acc, const float* __restrict__ part,
                              float* __restrict__ out) {
  int tid = threadIdx.x;                     // single block, 1024 threads
  float sA = 0.0f, sB = 0.0f, sP = 0.0f;
  for (int i = tid; i < B_;     i += 1024) sA += logf(acc[i]);
  for (int i = tid; i < NN_;    i += 1024) sB += logf(acc[B_ + i]);
  for (int i = tid; i < NPART_; i += 1024) sP += part[i];
  float s = sA * (1.0f / B_) + sB * (1.0f / NN_)
          - sP * (2.0f * M_SHIFT / (float)NN_);
  for (int o = 32; o; o >>= 1) s += __shfl_xor(s, o);
  __shared__ float ls[16];
  int lane = tid & 63, w = tid >> 6;
  if (lane == 0) ls[w] = s;
  __syncthreads();
  if (tid == 0) {
    float tot = 0.0f;
#pragma unroll
    for (int i = 0; i < 16; ++i) tot += ls[i];
    out[0] = M_SHIFT + 0.5f * tot;
  }
}

// ---------------------------------------------------------------------------
extern "C" void kernel_launch(void* const* d_in, const int* in_sizes, int n_in,
                              void* d_out, int out_size, void* d_ws, size_t ws_size,
                              hipStream_t stream) {
  const float* img = (const float*)d_in[0];   // (4096, 512) fp32
  const float* txt = (const float*)d_in[1];   // (4096, 5, 512) fp32

  // workspace: [ img_f16 | txt_f16 | row_sum(4096) col_sum(20480) part(2560) ]
  const size_t halfBytes = (size_t)(B_ * D_ + NN_ * D_) * 2;      // 25,165,824
  const size_t needBytes = halfBytes + (size_t)(B_ + NN_ + NPART_) * 4;
  if (ws_size < needBytes) return;            // fail loudly (absmax), don't fault

  _Float16* Ah  = (_Float16*)d_ws;            // B*D halves
  _Float16* Bh  = Ah + B_ * D_;               // NN*D halves
  float* acc    = (float*)((char*)d_ws + halfBytes);
  float* row_s  = acc;                        // [0, B_)
  float* col_s  = acc + B_;                   // [B_, B_+NN_)
  float* part   = acc + B_ + NN_;             // [B_+NN_, +NPART_)

  cvtpos_kernel<<<NPART_, 256, 0, stream>>>(img, txt, Ah, Bh, acc, part);
  gemm_kernel  <<<dim3(32, 160), 256, 0, stream>>>(Ah, Bh, row_s, col_s);
  finish_kernel<<<1, 1024, 0, stream>>>(acc, part, (float*)d_out);
}

// Round 8
// 200.867 us; speedup vs baseline: 1.6286x; 1.0458x over previous
//
#include <hip/hip_runtime.h>
#include <stdint.h>

// Shapes (fixed by the reference)
#define B_  4096
#define V_  5
#define D_  512
#define NN_ (B_ * V_)            // 20480 text rows
#define NPART_ 2560              // cvtpos blocks (grid-stride x4)

// p = exp((dot - 1)/T) = exp2(dot*C - C), C = log2(e)/T
#define C_EXP 20.609929155556620f   // 1.4426950408889634 / 0.07
#define M_SHIFT (1.0f / 0.07f)

typedef _Float16 half8   __attribute__((ext_vector_type(8)));
typedef float    floatx4 __attribute__((ext_vector_type(4)));

// async global->LDS DMA, 16B per lane; LDS dest = wave-uniform base + lane*16
__device__ __forceinline__ void load_lds16(const _Float16* g, _Float16* l) {
  __builtin_amdgcn_global_load_lds(
      (const __attribute__((address_space(1))) unsigned int*)g,
      (__attribute__((address_space(3))) unsigned int*)l,
      16, 0, 0);
}

// ---------------------------------------------------------------------------
// Kernel 1: fused fp32->f16 convert + possum partials + accumulator zeroing.
// 2560 blocks x 256 threads, each thread 4 float4s (exact cover of NN*D/4).
// Per-block partial store (round 3 proved same-address atomics serialize).
// ---------------------------------------------------------------------------
__global__ void cvtpos_kernel(const float* __restrict__ img, const float* __restrict__ txt,
                              _Float16* __restrict__ Ah, _Float16* __restrict__ Bh,
                              float* __restrict__ acc, float* __restrict__ part) {
  const int tid0 = blockIdx.x * 256 + threadIdx.x;
  if (tid0 < B_ + NN_) acc[tid0] = 0.0f;     // zero row/col sums (replaces memset)

  float s = 0.0f;
#pragma unroll
  for (int it = 0; it < 4; ++it) {           // 4 * 655360 = NN*D/4 exactly
    const int i  = tid0 + it * (NPART_ * 256);
    const int k4  = i & 127;                 // D/4 = 128
    const int row = i >> 7;                  // text row = i*V + v
    const int ii  = row / 5;                 // image index (magic-mul)
    float4 t = ((const float4*)txt)[i];
    float4 g = ((const float4*)img)[ii * 128 + k4];
    s += t.x * g.x + t.y * g.y + t.z * g.z + t.w * g.w;

    union { _Float16 h[4]; float2 f2; } u;
    u.h[0] = (_Float16)t.x; u.h[1] = (_Float16)t.y;
    u.h[2] = (_Float16)t.z; u.h[3] = (_Float16)t.w;
    ((float2*)Bh)[i] = u.f2;

    if (i < (B_ * D_) / 4) {                 // img convert (hits only it==0)
      float4 v = ((const float4*)img)[i];
      union { _Float16 h[4]; float2 f2; } wq;
      wq.h[0] = (_Float16)v.x; wq.h[1] = (_Float16)v.y;
      wq.h[2] = (_Float16)v.z; wq.h[3] = (_Float16)v.w;
      ((float2*)Ah)[i] = wq.f2;
    }
  }

  for (int o = 32; o; o >>= 1) s += __shfl_xor(s, o);
  __shared__ float ls[4];
  int lane = threadIdx.x & 63, w = threadIdx.x >> 6;
  if (lane == 0) ls[w] = s;
  __syncthreads();
  if (threadIdx.x == 0)
    part[blockIdx.x] = ls[0] + ls[1] + ls[2] + ls[3];   // raw dot-sum, no atomic
}

// ---------------------------------------------------------------------------
// Kernel 2: fused GEMM + exp + row/col partial sums — SUPERSTEP PIPELINE.
// 128x128 tile, BK=32, 4 waves (2x2), wave tile 64x64, XOR bank swizzle
// (0 conflicts, verified). Both LDS buffers are prefetched a full superstep
// (2 kt) ahead. Per superstep: barrier-A = the ONLY vmcnt-bearing drain
// (amortized over 2 kt; r7 paid it every kt); read all 16 frags; barrier-B
// (cheap: zero outstanding vmcnt, lgkm drain needed anyway); issue next
// superstep's DMAs; 32 MFMAs overlap those DMAs.
// grid = (32 m-tiles, 160 n-tiles); m fastest -> B-tile shared by 32 blocks.
// ---------------------------------------------------------------------------
__global__ __launch_bounds__(256, 3)
void gemm_kernel(const _Float16* __restrict__ Ah, const _Float16* __restrict__ Bh,
                 float* __restrict__ row_sum, float* __restrict__ col_sum) {
  __shared__ __align__(16) _Float16 As[2][128 * 32];   // 16 KB
  __shared__ __align__(16) _Float16 Bs[2][128 * 32];   // 16 KB
  const int tid  = threadIdx.x;
  const int lane = tid & 63;
  const int w    = tid >> 6;                 // wave 0..3
  const int wm   = w >> 1, wn = w & 1;       // 2x2 wave grid
  const int m0   = blockIdx.x * 128;
  const int n0   = blockIdx.y * 128;

  floatx4 acc[4][4] = {};

  // --- staging (swizzled): lane L -> LDS row L>>2, chunk L&3; global chunk
  // fetched is (L&3)^((L>>3)&3), i.e. LDS(r,c) = global chunk c^((r>>1)&3).
  const int sc = ((lane & 3) ^ ((lane >> 3) & 3)) * 8;     // halves
  const _Float16* gA = Ah + (size_t)(m0 + w * 32 + (lane >> 2)) * D_ + sc;
  const _Float16* gB = Bh + (size_t)(n0 + w * 32 + (lane >> 2)) * D_ + sc;
  const int lofs = (w * 32) * 32;            // wave-uniform LDS offset

  // --- fragment addressing (matching un-swizzle) ---
  const int fr = lane & 15;                  // frag m/n index (lane&15)
  const int fj = ((lane >> 4) ^ ((fr >> 1) & 3)) * 8;      // swizzled k-chunk

  // prologue: stage kt0 -> buf0, kt1 -> buf1
  load_lds16(gA,           &As[0][lofs]);
  load_lds16(gA + 16 * D_, &As[0][lofs + 16 * 32]);
  load_lds16(gB,           &Bs[0][lofs]);
  load_lds16(gB + 16 * D_, &Bs[0][lofs + 16 * 32]);
  load_lds16(gA + 32,           &As[1][lofs]);
  load_lds16(gA + 32 + 16 * D_, &As[1][lofs + 16 * 32]);
  load_lds16(gB + 32,           &Bs[1][lofs]);
  load_lds16(gB + 32 + 16 * D_, &Bs[1][lofs + 16 * 32]);

  for (int ss = 0; ss < 8; ++ss) {           // 8 supersteps x 2 kt = K/32
    __syncthreads();   // barrier A: drains DMAs issued a full superstep ago

    half8 af[2][4], bf[2][4];
#pragma unroll
    for (int p = 0; p < 2; ++p)
#pragma unroll
      for (int f = 0; f < 4; ++f) {
        af[p][f] = *(const half8*)(&As[p][(wm * 64 + f * 16 + fr) * 32 + fj]);
        bf[p][f] = *(const half8*)(&Bs[p][(wn * 64 + f * 16 + fr) * 32 + fj]);
      }

    __syncthreads();   // barrier B: cheap (vmcnt already 0; lgkm drain needed anyway)

    if (ss < 7) {      // stage superstep ss+1 (overlaps the MFMAs below)
      const int kg = (2 * ss + 2) * 32;
      load_lds16(gA + kg,                &As[0][lofs]);
      load_lds16(gA + kg + 16 * D_,      &As[0][lofs + 16 * 32]);
      load_lds16(gB + kg,                &Bs[0][lofs]);
      load_lds16(gB + kg + 16 * D_,      &Bs[0][lofs + 16 * 32]);
      load_lds16(gA + kg + 32,           &As[1][lofs]);
      load_lds16(gA + kg + 32 + 16 * D_, &As[1][lofs + 16 * 32]);
      load_lds16(gB + kg + 32,           &Bs[1][lofs]);
      load_lds16(gB + kg + 32 + 16 * D_, &Bs[1][lofs + 16 * 32]);
    }

#pragma unroll
    for (int p = 0; p < 2; ++p)
#pragma unroll
      for (int mf = 0; mf < 4; ++mf)
#pragma unroll
        for (int nf = 0; nf < 4; ++nf)
          acc[mf][nf] = __builtin_amdgcn_mfma_f32_16x16x32_f16(af[p][mf], bf[p][nf], acc[mf][nf], 0, 0, 0);
  }

  // Epilogue: p = exp2(dot*C - C); C/D layout: col=lane&15, row=(lane>>4)*4+reg
#pragma unroll
  for (int mf = 0; mf < 4; ++mf)
#pragma unroll
    for (int nf = 0; nf < 4; ++nf)
#pragma unroll
      for (int r = 0; r < 4; ++r)
        acc[mf][nf][r] = exp2f(acc[mf][nf][r] * C_EXP - C_EXP);

  // column sums over this wave's 64 rows
  float cs[4];
#pragma unroll
  for (int nf = 0; nf < 4; ++nf) {
    float s = 0.0f;
#pragma unroll
    for (int mf = 0; mf < 4; ++mf)
      s += acc[mf][nf][0] + acc[mf][nf][1] + acc[mf][nf][2] + acc[mf][nf][3];
    s += __shfl_xor(s, 16);
    s += __shfl_xor(s, 32);
    cs[nf] = s;
  }
  {
    int g = lane >> 4;                        // lane group g holds frag g's sums
    float v = (g == 0) ? cs[0] : (g == 1) ? cs[1] : (g == 2) ? cs[2] : cs[3];
    atomicAdd(&col_sum[n0 + wn * 64 + (g << 4) + (lane & 15)], v);
  }

  // row sums over this wave's 64 cols
#pragma unroll
  for (int mf = 0; mf < 4; ++mf) {
    floatx4 t = acc[mf][0] + acc[mf][1] + acc[mf][2] + acc[mf][3];
#pragma unroll
    for (int r = 0; r < 4; ++r) {
      float s = t[r];
      s += __shfl_xor(s, 1); s += __shfl_xor(s, 2);
      s += __shfl_xor(s, 4); s += __shfl_xor(s, 8);
      t[r] = s;
    }
    if ((lane & 15) < 4) {                    // 16 lanes cover 16 rows of this m-frag
      int q = lane & 3;
      float v = (q == 0) ? t[0] : (q == 1) ? t[1] : (q == 2) ? t[2] : t[3];
      atomicAdd(&row_sum[m0 + wm * 64 + mf * 16 + ((lane >> 4) << 2) + q], v);
    }
  }
}

// ---------------------------------------------------------------------------
// Kernel 3: loss = M + 0.5*(mean log rowsum + mean log colsum - 2*pos/(BV))
// pos = M_SHIFT * sum(part).  All linear -> single fused block reduction.
// ---------------------------------------------------------------------------
__global__ void finish_kernel(const float* __restrict__ acc, const float* __restrict__ part,
                              float* __restrict__ out) {
  int tid = threadIdx.x;                     // single block, 1024 threads
  float sA = 0.0f, sB = 0.0f, sP = 0.0f;
  for (int i = tid; i < B_;     i += 1024) sA += logf(acc[i]);
  for (int i = tid; i < NN_;    i += 1024) sB += logf(acc[B_ + i]);
  for (int i = tid; i < NPART_; i += 1024) sP += part[i];
  float s = sA * (1.0f / B_) + sB * (1.0f / NN_)
          - sP * (2.0f * M_SHIFT / (float)NN_);
  for (int o = 32; o; o >>= 1) s += __shfl_xor(s, o);
  __shared__ float ls[16];
  int lane = tid & 63, w = tid >> 6;
  if (lane == 0) ls[w] = s;
  __syncthreads();
  if (tid == 0) {
    float tot = 0.0f;
#pragma unroll
    for (int i = 0; i < 16; ++i) tot += ls[i];
    out[0] = M_SHIFT + 0.5f * tot;
  }
}

// ---------------------------------------------------------------------------
extern "C" void kernel_launch(void* const* d_in, const int* in_sizes, int n_in,
                              void* d_out, int out_size, void* d_ws, size_t ws_size,
                              hipStream_t stream) {
  const float* img = (const float*)d_in[0];   // (4096, 512) fp32
  const float* txt = (const float*)d_in[1];   // (4096, 5, 512) fp32

  // workspace: [ img_f16 | txt_f16 | row_sum(4096) col_sum(20480) part(2560) ]
  const size_t halfBytes = (size_t)(B_ * D_ + NN_ * D_) * 2;      // 25,165,824
  const size_t needBytes = halfBytes + (size_t)(B_ + NN_ + NPART_) * 4;
  if (ws_size < needBytes) return;            // fail loudly (absmax), don't fault

  _Float16* Ah  = (_Float16*)d_ws;            // B*D halves
  _Float16* Bh  = Ah + B_ * D_;               // NN*D halves
  float* acc    = (float*)((char*)d_ws + halfBytes);
  float* row_s  = acc;                        // [0, B_)
  float* col_s  = acc + B_;                   // [B_, B_+NN_)
  float* part   = acc + B_ + NN_;             // [B_+NN_, +NPART_)

  cvtpos_kernel<<<NPART_, 256, 0, stream>>>(img, txt, Ah, Bh, acc, part);
  gemm_kernel  <<<dim3(32, 160), 256, 0, stream>>>(Ah, Bh, row_s, col_s);
  finish_kernel<<<1, 1024, 0, stream>>>(acc, part, (float*)d_out);
}

// Round 9
// 200.538 us; speedup vs baseline: 1.6312x; 1.0016x over previous
//
#include <hip/hip_runtime.h>
#include <stdint.h>

// Shapes (fixed by the reference)
#define B_  4096
#define V_  5
#define D_  512
#define NN_ (B_ * V_)            // 20480 text rows
#define NBLK_ 5120               // gemm grid 32 x 160

// p = exp((dot - 1)/T) = exp2(dot*C - C), C = log2(e)/T
#define C_EXP 20.609929155556620f   // 1.4426950408889634 / 0.07
#define M_SHIFT (1.0f / 0.07f)

typedef _Float16 half8   __attribute__((ext_vector_type(8)));
typedef float    floatx4 __attribute__((ext_vector_type(4)));

// async global->LDS DMA, 16B per lane; LDS dest = wave-uniform base + lane*16
__device__ __forceinline__ void load_lds16(const _Float16* g, _Float16* l) {
  __builtin_amdgcn_global_load_lds(
      (const __attribute__((address_space(1))) unsigned int*)g,
      (__attribute__((address_space(3))) unsigned int*)l,
      16, 0, 0);
}

// ---------------------------------------------------------------------------
// Kernel 1: PURE streaming fp32->f16 convert + accumulator zeroing.
// 2048 blocks x 256 threads x 6 float4 = 3,145,728 float4s exact.
// it==0 covers img exactly (524288), it>=1 covers txt — the select is
// compile-time, no runtime branch. No gather, no reduce, no barrier (r8
// showed the non-GEMM residue is NOT block-count-bound; possum moved into
// the GEMM epilogue where the dots already exist).
// ---------------------------------------------------------------------------
__global__ void cvt_kernel(const float* __restrict__ img, const float* __restrict__ txt,
                           _Float16* __restrict__ outH, float* __restrict__ acc) {
  const int tid0 = blockIdx.x * 256 + threadIdx.x;
  if (tid0 < B_ + NN_) acc[tid0] = 0.0f;     // zero row/col sums
#pragma unroll
  for (int it = 0; it < 6; ++it) {
    const int i = tid0 + it * (2048 * 256);
    float4 v = (it == 0) ? ((const float4*)img)[i]
                         : ((const float4*)txt)[i - (B_ * D_) / 4];
    union { _Float16 h[4]; float2 f2; } u;
    u.h[0] = (_Float16)v.x; u.h[1] = (_Float16)v.y;
    u.h[2] = (_Float16)v.z; u.h[3] = (_Float16)v.w;
    ((float2*)outH)[i] = u.f2;
  }
}

// ---------------------------------------------------------------------------
// Kernel 2: fused GEMM + exp + row/col partial sums + POSITIVE extraction.
// Superstep pipeline (r8: 113.5us, MfmaUtil 34%): 128x128 tile, BK=32,
// 4 waves 2x2, XOR bank swizzle (0 conflicts), both LDS buffers prefetched
// a full superstep (2 kt) ahead -> one vmcnt-bearing drain per 2 kt.
// NEW: positives (row == col/5) summed from raw acc pre-exp, one partial
// per block (each positive cell lives in exactly one block).
// ---------------------------------------------------------------------------
__global__ __launch_bounds__(256, 3)
void gemm_kernel(const _Float16* __restrict__ Ah, const _Float16* __restrict__ Bh,
                 float* __restrict__ row_sum, float* __restrict__ col_sum,
                 float* __restrict__ posPart) {
  __shared__ __align__(16) _Float16 As[2][128 * 32];   // 16 KB
  __shared__ __align__(16) _Float16 Bs[2][128 * 32];   // 16 KB
  const int tid  = threadIdx.x;
  const int lane = tid & 63;
  const int w    = tid >> 6;                 // wave 0..3
  const int wm   = w >> 1, wn = w & 1;       // 2x2 wave grid
  const int m0   = blockIdx.x * 128;
  const int n0   = blockIdx.y * 128;

  floatx4 acc[4][4] = {};

  // --- staging (swizzled): lane L -> LDS row L>>2, chunk L&3; global chunk
  // fetched is (L&3)^((L>>3)&3), i.e. LDS(r,c) = global chunk c^((r>>1)&3).
  const int sc = ((lane & 3) ^ ((lane >> 3) & 3)) * 8;     // halves
  const _Float16* gA = Ah + (size_t)(m0 + w * 32 + (lane >> 2)) * D_ + sc;
  const _Float16* gB = Bh + (size_t)(n0 + w * 32 + (lane >> 2)) * D_ + sc;
  const int lofs = (w * 32) * 32;            // wave-uniform LDS offset

  // --- fragment addressing (matching un-swizzle) ---
  const int fr = lane & 15;                  // frag m/n index (lane&15)
  const int fj = ((lane >> 4) ^ ((fr >> 1) & 3)) * 8;      // swizzled k-chunk

  // prologue: stage kt0 -> buf0, kt1 -> buf1
  load_lds16(gA,           &As[0][lofs]);
  load_lds16(gA + 16 * D_, &As[0][lofs + 16 * 32]);
  load_lds16(gB,           &Bs[0][lofs]);
  load_lds16(gB + 16 * D_, &Bs[0][lofs + 16 * 32]);
  load_lds16(gA + 32,           &As[1][lofs]);
  load_lds16(gA + 32 + 16 * D_, &As[1][lofs + 16 * 32]);
  load_lds16(gB + 32,           &Bs[1][lofs]);
  load_lds16(gB + 32 + 16 * D_, &Bs[1][lofs + 16 * 32]);

  for (int ss = 0; ss < 8; ++ss) {           // 8 supersteps x 2 kt = K/32
    __syncthreads();   // barrier A: drains DMAs issued a full superstep ago

    half8 af[2][4], bf[2][4];
#pragma unroll
    for (int p = 0; p < 2; ++p)
#pragma unroll
      for (int f = 0; f < 4; ++f) {
        af[p][f] = *(const half8*)(&As[p][(wm * 64 + f * 16 + fr) * 32 + fj]);
        bf[p][f] = *(const half8*)(&Bs[p][(wn * 64 + f * 16 + fr) * 32 + fj]);
      }

    __syncthreads();   // barrier B: cheap (vmcnt already 0; lgkm drain needed anyway)

    if (ss < 7) {      // stage superstep ss+1 (overlaps the MFMAs below)
      const int kg = (2 * ss + 2) * 32;
      load_lds16(gA + kg,                &As[0][lofs]);
      load_lds16(gA + kg + 16 * D_,      &As[0][lofs + 16 * 32]);
      load_lds16(gB + kg,                &Bs[0][lofs]);
      load_lds16(gB + kg + 16 * D_,      &Bs[0][lofs + 16 * 32]);
      load_lds16(gA + kg + 32,           &As[1][lofs]);
      load_lds16(gA + kg + 32 + 16 * D_, &As[1][lofs + 16 * 32]);
      load_lds16(gB + kg + 32,           &Bs[1][lofs]);
      load_lds16(gB + kg + 32 + 16 * D_, &Bs[1][lofs + 16 * 32]);
    }

#pragma unroll
    for (int p = 0; p < 2; ++p)
#pragma unroll
      for (int mf = 0; mf < 4; ++mf)
#pragma unroll
        for (int nf = 0; nf < 4; ++nf)
          acc[mf][nf] = __builtin_amdgcn_mfma_f32_16x16x32_f16(af[p][mf], bf[p][nf], acc[mf][nf], 0, 0, 0);
  }

  // --- positive extraction from RAW acc (pre-exp): row == col/5 ---
  {
    float ps = 0.0f;
    const int iLo = n0 / 5, iHi = (n0 + 127) / 5;
    if (iHi >= m0 && iLo < m0 + 128) {       // block-uniform skip (~4/5 skip)
      const int rbase = m0 + wm * 64 + ((lane >> 4) << 2);
#pragma unroll
      for (int nf = 0; nf < 4; ++nf) {
        const int ci = (n0 + wn * 64 + nf * 16 + (lane & 15)) / 5;
#pragma unroll
        for (int mf = 0; mf < 4; ++mf)
#pragma unroll
          for (int r = 0; r < 4; ++r)
            if (rbase + mf * 16 + r == ci) ps += acc[mf][nf][r];
      }
    }
    for (int o = 32; o; o >>= 1) ps += __shfl_xor(ps, o);
    __shared__ float pls[4];
    if (lane == 0) pls[w] = ps;
    __syncthreads();
    if (tid == 0)
      posPart[blockIdx.y * 32 + blockIdx.x] = pls[0] + pls[1] + pls[2] + pls[3];
  }

  // Epilogue: p = exp2(dot*C - C); C/D layout: col=lane&15, row=(lane>>4)*4+reg
#pragma unroll
  for (int mf = 0; mf < 4; ++mf)
#pragma unroll
    for (int nf = 0; nf < 4; ++nf)
#pragma unroll
      for (int r = 0; r < 4; ++r)
        acc[mf][nf][r] = exp2f(acc[mf][nf][r] * C_EXP - C_EXP);

  // column sums over this wave's 64 rows
  float cs[4];
#pragma unroll
  for (int nf = 0; nf < 4; ++nf) {
    float s = 0.0f;
#pragma unroll
    for (int mf = 0; mf < 4; ++mf)
      s += acc[mf][nf][0] + acc[mf][nf][1] + acc[mf][nf][2] + acc[mf][nf][3];
    s += __shfl_xor(s, 16);
    s += __shfl_xor(s, 32);
    cs[nf] = s;
  }
  {
    int g = lane >> 4;                        // lane group g holds frag g's sums
    float v = (g == 0) ? cs[0] : (g == 1) ? cs[1] : (g == 2) ? cs[2] : cs[3];
    atomicAdd(&col_sum[n0 + wn * 64 + (g << 4) + (lane & 15)], v);
  }

  // row sums over this wave's 64 cols
#pragma unroll
  for (int mf = 0; mf < 4; ++mf) {
    floatx4 t = acc[mf][0] + acc[mf][1] + acc[mf][2] + acc[mf][3];
#pragma unroll
    for (int r = 0; r < 4; ++r) {
      float s = t[r];
      s += __shfl_xor(s, 1); s += __shfl_xor(s, 2);
      s += __shfl_xor(s, 4); s += __shfl_xor(s, 8);
      t[r] = s;
    }
    if ((lane & 15) < 4) {                    // 16 lanes cover 16 rows of this m-frag
      int q = lane & 3;
      float v = (q == 0) ? t[0] : (q == 1) ? t[1] : (q == 2) ? t[2] : t[3];
      atomicAdd(&row_sum[m0 + wm * 64 + mf * 16 + ((lane >> 4) << 2) + q], v);
    }
  }
}

// ---------------------------------------------------------------------------
// Kernel 3: loss = M + 0.5*(mean log rowsum + mean log colsum - 2*pos/(BV))
// pos (in dot units) = sum(posPart); scaled by M_SHIFT here.
// ---------------------------------------------------------------------------
__global__ void finish_kernel(const float* __restrict__ acc, const float* __restrict__ posPart,
                              float* __restrict__ out) {
  int tid = threadIdx.x;                     // single block, 1024 threads
  float sA = 0.0f, sB = 0.0f, sP = 0.0f;
  for (int i = tid; i < B_;    i += 1024) sA += logf(acc[i]);
  for (int i = tid; i < NN_;   i += 1024) sB += logf(acc[B_ + i]);
  for (int i = tid; i < NBLK_; i += 1024) sP += posPart[i];
  float s = sA * (1.0f / B_) + sB * (1.0f / NN_)
          - sP * (2.0f * M_SHIFT / (float)NN_);
  for (int o = 32; o; o >>= 1) s += __shfl_xor(s, o);
  __shared__ float ls[16];
  int lane = tid & 63, w = tid >> 6;
  if (lane == 0) ls[w] = s;
  __syncthreads();
  if (tid == 0) {
    float tot = 0.0f;
#pragma unroll
    for (int i = 0; i < 16; ++i) tot += ls[i];
    out[0] = M_SHIFT + 0.5f * tot;
  }
}

// ---------------------------------------------------------------------------
extern "C" void kernel_launch(void* const* d_in, const int* in_sizes, int n_in,
                              void* d_out, int out_size, void* d_ws, size_t ws_size,
                              hipStream_t stream) {
  const float* img = (const float*)d_in[0];   // (4096, 512) fp32
  const float* txt = (const float*)d_in[1];   // (4096, 5, 512) fp32

  // workspace: [ img_f16 | txt_f16 | row_sum(4096) col_sum(20480) posPart(5120) ]
  const size_t halfBytes = (size_t)(B_ * D_ + NN_ * D_) * 2;      // 25,165,824
  const size_t needBytes = halfBytes + (size_t)(B_ + NN_ + NBLK_) * 4;
  if (ws_size < needBytes) return;            // fail loudly (absmax), don't fault

  _Float16* Ah  = (_Float16*)d_ws;            // B*D halves (txt follows contiguously)
  _Float16* Bh  = Ah + B_ * D_;               // NN*D halves
  float* acc    = (float*)((char*)d_ws + halfBytes);
  float* row_s  = acc;                        // [0, B_)
  float* col_s  = acc + B_;                   // [B_, B_+NN_)
  float* posP   = acc + B_ + NN_;             // [B_+NN_, +NBLK_)

  cvt_kernel   <<<2048, 256, 0, stream>>>(img, txt, Ah, acc);
  gemm_kernel  <<<dim3(32, 160), 256, 0, stream>>>(Ah, Bh, row_s, col_s, posP);
  finish_kernel<<<1, 1024, 0, stream>>>(acc, posP, (float*)d_out);
}